// Round 1
// baseline (10370.453 us; speedup 1.0000x reference)
//
#include <hip/hip_runtime.h>
#include <math.h>

#define NN 100000
#define NR 8
#define NE 640000
#define CHUNK 32
#define NCHUNKS (NE / CHUNK + NR)   // 20008
#define EBUCK_N (NCHUNKS * CHUNK)   // 640256

// ---------------- preprocessing kernels ----------------

__global__ void count_kernel(const int* __restrict__ dst, const int* __restrict__ et,
                             unsigned* __restrict__ cnt, unsigned* __restrict__ relcnt) {
    int e = blockIdx.x * 256 + threadIdx.x;
    if (e >= NE) return;
    atomicAdd(&cnt[(size_t)dst[e] * NR + et[e]], 1u);
    atomicAdd(&relcnt[et[e]], 1u);
}

__global__ void offsets_kernel(const unsigned* __restrict__ relcnt, int* __restrict__ off) {
    int acc = 0;
    for (int r = 0; r < NR; ++r) {
        off[r] = acc;
        acc += (int)((relcnt[r] + CHUNK - 1) / CHUNK) * CHUNK;
    }
    off[NR] = acc;
}

__global__ void fill_kernel(const int* __restrict__ et, const int* __restrict__ off,
                            unsigned* __restrict__ cursor, int* __restrict__ ebuck) {
    int e = blockIdx.x * 256 + threadIdx.x;
    if (e >= NE) return;
    int r = et[e];
    int pos = off[r] + (int)atomicAdd(&cursor[r], 1u);
    ebuck[pos] = e;
}

__global__ void inv_kernel(const unsigned* __restrict__ cnt, float* __restrict__ inv) {
    int s = blockIdx.x * 256 + threadIdx.x;
    if (s >= NN * NR) return;
    unsigned c = cnt[s];
    inv[s] = 1.0f / (float)(c > 0u ? c : 1u);
}

// ---------------- edge transform-scatter GEMM ----------------
// Each block: 32 edges, all same relation (bucketed, padded with -1).
// y_e = x[src_e] @ W[rel] * inv_cnt[dst_e,rel], atomicAdd into acc[dst_e].

template <int D, int O>
__global__ __launch_bounds__(256) void edge_gemm(
    const float* __restrict__ x, const float* __restrict__ W,
    const int* __restrict__ ebuck, const int* __restrict__ src,
    const int* __restrict__ dst, const int* __restrict__ et,
    const float* __restrict__ inv, float* __restrict__ acc)
{
    __shared__ float sxT[D][CHUNK + 1];   // transposed x rows (pad -> conflict-free)
    __shared__ float sW[32][O];           // K-chunk of W[rel]
    __shared__ int   s_e[CHUNK];
    __shared__ int   s_dst[CHUNK];
    __shared__ float s_scl[CHUNK];
    __shared__ int   s_rel;

    int t = threadIdx.x;
    int c = blockIdx.x;

    if (t < CHUNK) s_e[t] = ebuck[c * CHUNK + t];
    if (t == 0) s_rel = -1;
    __syncthreads();
    if (t == 0) {
        for (int j = 0; j < CHUNK; ++j)
            if (s_e[j] >= 0) { s_rel = et[s_e[j]]; break; }
    }
    __syncthreads();
    int rel = s_rel;
    if (rel < 0) return;   // fully padded chunk

    if (t < CHUNK) {
        int e = s_e[t];
        int d = (e >= 0) ? dst[e] : 0;
        s_dst[t] = d;
        s_scl[t] = (e >= 0) ? inv[(size_t)d * NR + rel] : 0.0f;
    }
    // stage x rows transposed: sxT[i][j]
    for (int idx = t; idx < CHUNK * D; idx += 256) {
        int j = idx / D, i = idx % D;
        int e = s_e[j];
        sxT[i][j] = (e >= 0) ? x[(size_t)src[e] * D + i] : 0.0f;
    }

    constexpr int TO  = O / 4;        // o-groups (each covers 4 outputs)
    constexpr int TG  = 256 / TO;     // edge-groups
    constexpr int EPG = CHUNK / TG;   // edges per thread
    int to = t % TO;
    int te = t / TO;
    int je0 = te * EPG;

    float racc[EPG][4];
#pragma unroll
    for (int m = 0; m < EPG; ++m)
#pragma unroll
        for (int q = 0; q < 4; ++q) racc[m][q] = 0.0f;

    for (int kc = 0; kc < D; kc += 32) {
        __syncthreads();
        for (int idx = t; idx < 32 * O; idx += 256) {
            int ii = idx / O, oo = idx % O;
            sW[ii][oo] = W[(size_t)rel * D * O + (size_t)(kc + ii) * O + oo];
        }
        __syncthreads();
#pragma unroll
        for (int ii = 0; ii < 32; ++ii) {
            int i = kc + ii;
            float4 b = *(const float4*)&sW[ii][to * 4];
#pragma unroll
            for (int m = 0; m < EPG; ++m) {
                float a = sxT[i][je0 + m];
                racc[m][0] += a * b.x;
                racc[m][1] += a * b.y;
                racc[m][2] += a * b.z;
                racc[m][3] += a * b.w;
            }
        }
    }

#pragma unroll
    for (int m = 0; m < EPG; ++m) {
        int j = je0 + m;
        int e = s_e[j];
        if (e < 0) continue;
        float scl = s_scl[j];
        float* ap = acc + (size_t)s_dst[j] * O + to * 4;
#pragma unroll
        for (int q = 0; q < 4; ++q) atomicAdd(&ap[q], racc[m][q] * scl);
    }
}

// ---------------- epilogue: root GEMM + bias + relu/resid/LN ----------------
// MODE 0: relu + LN        (layer 1)
// MODE 1: relu + identity + LN  (layer 2, D==O==128)
// MODE 2: relu only        (layer 3)
// MODE 3: plain            (layer 4)

template <int D, int O, int MODE>
__global__ __launch_bounds__(256) void epilogue_kernel(
    const float* __restrict__ x, const float* __restrict__ Wr,
    const float* __restrict__ bias, const float* __restrict__ acc,
    const float* __restrict__ gamma, const float* __restrict__ beta,
    float* __restrict__ out)
{
    constexpr int NT  = 16;
    constexpr int G   = 256 / O;   // node groups
    constexpr int NPT = NT / G;    // nodes per thread
    __shared__ float sx[NT][D];
    __shared__ float sW[32][O];

    int t  = threadIdx.x;
    int n0 = blockIdx.x * NT;
    int o  = t % O;
    int ng = t / O;

    for (int idx = t; idx < NT * D; idx += 256) {
        int j = idx / D, i = idx % D;
        sx[j][i] = x[(size_t)(n0 + j) * D + i];
    }

    float r[NPT];
#pragma unroll
    for (int k = 0; k < NPT; ++k) r[k] = 0.0f;

    for (int kc = 0; kc < D; kc += 32) {
        __syncthreads();
        for (int idx = t; idx < 32 * O; idx += 256) {
            int ii = idx / O, oo = idx % O;
            sW[ii][oo] = Wr[(size_t)(kc + ii) * O + oo];
        }
        __syncthreads();
#pragma unroll
        for (int ii = 0; ii < 32; ++ii) {
            float w = sW[ii][o];
#pragma unroll
            for (int k = 0; k < NPT; ++k)
                r[k] += sx[ng + G * k][kc + ii] * w;
        }
    }

    float bo = bias[o];
    float vv[NPT];
#pragma unroll
    for (int k = 0; k < NPT; ++k) {
        int n = n0 + ng + G * k;
        float v = r[k] + acc[(size_t)n * O + o] + bo;
        if constexpr (MODE <= 2) v = fmaxf(v, 0.0f);
        if constexpr (MODE == 1) v += sx[ng + G * k][o];   // residual (D==O)
        vv[k] = v;
    }

    if constexpr (MODE == 0 || MODE == 1) {
        // LayerNorm over O=128 values (2 waves per node group)
        __shared__ float sS[4][NPT], sQ[4][NPT];
        int wid = t >> 6;
#pragma unroll
        for (int k = 0; k < NPT; ++k) {
            float s1 = vv[k], s2 = vv[k] * vv[k];
#pragma unroll
            for (int off = 32; off >= 1; off >>= 1) {
                s1 += __shfl_xor(s1, off, 64);
                s2 += __shfl_xor(s2, off, 64);
            }
            if ((t & 63) == 0) { sS[wid][k] = s1; sQ[wid][k] = s2; }
        }
        __syncthreads();
        float go = gamma[o], bto = beta[o];
#pragma unroll
        for (int k = 0; k < NPT; ++k) {
            float s1 = sS[2 * ng][k] + sS[2 * ng + 1][k];
            float s2 = sQ[2 * ng][k] + sQ[2 * ng + 1][k];
            float mu  = s1 * (1.0f / O);
            float var = s2 * (1.0f / O) - mu * mu;
            float rs  = rsqrtf(var + 1e-5f);
            int n = n0 + ng + G * k;
            out[(size_t)n * O + o] = (vv[k] - mu) * rs * go + bto;
        }
    } else {
#pragma unroll
        for (int k = 0; k < NPT; ++k) {
            int n = n0 + ng + G * k;
            out[(size_t)n * O + o] = vv[k];
        }
    }
}

// ---------------- host launch ----------------

extern "C" void kernel_launch(void* const* d_in, const int* in_sizes, int n_in,
                              void* d_out, int out_size, void* d_ws, size_t ws_size,
                              hipStream_t stream) {
    const float* emb = (const float*)d_in[0];
    const float* W1  = (const float*)d_in[1];
    const float* R1  = (const float*)d_in[2];
    const float* B1  = (const float*)d_in[3];
    const float* W2  = (const float*)d_in[4];
    const float* R2  = (const float*)d_in[5];
    const float* B2  = (const float*)d_in[6];
    const float* W3  = (const float*)d_in[7];
    const float* R3  = (const float*)d_in[8];
    const float* B3  = (const float*)d_in[9];
    const float* W4  = (const float*)d_in[10];
    const float* R4  = (const float*)d_in[11];
    const float* B4  = (const float*)d_in[12];
    const float* g1  = (const float*)d_in[13];
    const float* b1  = (const float*)d_in[14];
    const float* g2  = (const float*)d_in[15];
    const float* b2  = (const float*)d_in[16];
    const int*   ei  = (const int*)d_in[17];
    const int*   et  = (const int*)d_in[18];
    const int* srcp = ei;
    const int* dstp = ei + NE;

    char* ws = (char*)d_ws;
    // layout (bytes):
    // cnt   u32[800000]          @ 0
    // inv   f32[800000]          @ 3,200,000
    // meta  i32[64]              @ 6,400,000   (off[0..8]; relcnt @ +16; cursor @ +24)
    // ebuck i32[640256]          @ 6,400,256
    // acc   f32[100000*128]      @ 8,961,280
    // x1    f32[100000*128]      @ 60,161,280
    // x2    f32[100000*128]      @ 111,361,280
    // x3    f32[100000*64]       @ 162,561,280  (end 188,161,280)
    if (ws_size < 188161280u) return;
    unsigned* cnt    = (unsigned*)(ws + 0);
    float*    inv    = (float*)(ws + 3200000);
    int*      meta   = (int*)(ws + 6400000);
    int*      off    = meta;
    unsigned* relcnt = (unsigned*)(meta + 16);
    unsigned* cursor = (unsigned*)(meta + 24);
    int*      ebuck  = (int*)(ws + 6400256);
    float*    acc    = (float*)(ws + 8961280);
    float*    x1     = (float*)(ws + 60161280);
    float*    x2     = (float*)(ws + 111361280);
    float*    x3     = (float*)(ws + 162561280);
    float*    outp   = (float*)d_out;

    hipMemsetAsync(cnt, 0, 3200000, stream);
    hipMemsetAsync(meta, 0, 256, stream);
    hipMemsetAsync(ebuck, 0xFF, (size_t)EBUCK_N * 4, stream);

    count_kernel<<<(NE + 255) / 256, 256, 0, stream>>>(dstp, et, cnt, relcnt);
    offsets_kernel<<<1, 1, 0, stream>>>(relcnt, off);
    fill_kernel<<<(NE + 255) / 256, 256, 0, stream>>>(et, off, cursor, ebuck);
    inv_kernel<<<(NN * NR + 255) / 256, 256, 0, stream>>>(cnt, inv);

    // Layer 1: emb(D=64) -> x1(O=128), relu + LN(g1,b1)
    hipMemsetAsync(acc, 0, (size_t)NN * 128 * 4, stream);
    edge_gemm<64, 128><<<NCHUNKS, 256, 0, stream>>>(emb, W1, ebuck, srcp, dstp, et, inv, acc);
    epilogue_kernel<64, 128, 0><<<NN / 16, 256, 0, stream>>>(emb, R1, B1, acc, g1, b1, x1);

    // Layer 2: x1(128) -> x2(128), relu + residual + LN(g2,b2)
    hipMemsetAsync(acc, 0, (size_t)NN * 128 * 4, stream);
    edge_gemm<128, 128><<<NCHUNKS, 256, 0, stream>>>(x1, W2, ebuck, srcp, dstp, et, inv, acc);
    epilogue_kernel<128, 128, 1><<<NN / 16, 256, 0, stream>>>(x1, R2, B2, acc, g2, b2, x2);

    // Layer 3: x2(128) -> x3(64), relu
    hipMemsetAsync(acc, 0, (size_t)NN * 64 * 4, stream);
    edge_gemm<128, 64><<<NCHUNKS, 256, 0, stream>>>(x2, W3, ebuck, srcp, dstp, et, inv, acc);
    epilogue_kernel<128, 64, 2><<<NN / 16, 256, 0, stream>>>(x2, R3, B3, acc, nullptr, nullptr, x3);

    // Layer 4: x3(64) -> out(64), plain
    hipMemsetAsync(acc, 0, (size_t)NN * 64 * 4, stream);
    edge_gemm<64, 64><<<NCHUNKS, 256, 0, stream>>>(x3, W4, ebuck, srcp, dstp, et, inv, acc);
    epilogue_kernel<64, 64, 3><<<NN / 16, 256, 0, stream>>>(x3, R4, B4, acc, nullptr, nullptr, outp);
}

// Round 2
// 4782.884 us; speedup vs baseline: 2.1682x; 2.1682x over previous
//
#include <hip/hip_runtime.h>
#include <math.h>

#define NN 100000
#define NR 8
#define NE 640000
#define CHUNK 32
#define NCHUNKS (NE / CHUNK + NR)   // 20008
#define EBUCK_N (NCHUNKS * CHUNK)   // 640256
#define EPB 1024                    // edges per preprocessing block

// ---------------- preprocessing kernels ----------------

__global__ __launch_bounds__(256) void count_kernel(
    const int* __restrict__ dst, const int* __restrict__ et,
    unsigned* __restrict__ cnt, unsigned* __restrict__ relcnt) {
    __shared__ unsigned lrel[NR];
    int t = threadIdx.x;
    if (t < NR) lrel[t] = 0;
    __syncthreads();
    int e0 = blockIdx.x * EPB;
#pragma unroll
    for (int k = 0; k < EPB / 256; ++k) {
        int e = e0 + k * 256 + t;
        if (e < NE) {
            int r = et[e];
            atomicAdd(&cnt[(size_t)dst[e] * NR + r], 1u);  // 800K addrs, low contention
            atomicAdd(&lrel[r], 1u);                        // LDS, block-local
        }
    }
    __syncthreads();
    if (t < NR) atomicAdd(&relcnt[t], lrel[t]);             // 8 atomics per block
}

__global__ void offsets_kernel(const unsigned* __restrict__ relcnt, int* __restrict__ off) {
    int acc = 0;
    for (int r = 0; r < NR; ++r) {
        off[r] = acc;
        acc += (int)((relcnt[r] + CHUNK - 1) / CHUNK) * CHUNK;
    }
    off[NR] = acc;
}

__global__ __launch_bounds__(256) void fill_kernel(
    const int* __restrict__ et, const int* __restrict__ off,
    unsigned* __restrict__ cursor, int* __restrict__ ebuck) {
    __shared__ unsigned lcnt[NR];
    __shared__ unsigned lbase[NR];
    int t = threadIdx.x;
    if (t < NR) lcnt[t] = 0;
    __syncthreads();
    int e0 = blockIdx.x * EPB;
    int myrel[EPB / 256];
    unsigned myrank[EPB / 256];
#pragma unroll
    for (int k = 0; k < EPB / 256; ++k) {
        int e = e0 + k * 256 + t;
        if (e < NE) {
            int r = et[e];
            myrel[k] = r;
            myrank[k] = atomicAdd(&lcnt[r], 1u);            // LDS rank within block
        } else {
            myrel[k] = -1;
        }
    }
    __syncthreads();
    if (t < NR) lbase[t] = atomicAdd(&cursor[t], lcnt[t]);  // 8 global atomics per block
    __syncthreads();
#pragma unroll
    for (int k = 0; k < EPB / 256; ++k) {
        if (myrel[k] >= 0) {
            int e = e0 + k * 256 + t;
            int r = myrel[k];
            ebuck[off[r] + (int)(lbase[r] + myrank[k])] = e;
        }
    }
}

__global__ void inv_kernel(const unsigned* __restrict__ cnt, float* __restrict__ inv) {
    int s = blockIdx.x * 256 + threadIdx.x;
    if (s >= NN * NR) return;
    unsigned c = cnt[s];
    inv[s] = 1.0f / (float)(c > 0u ? c : 1u);
}

// ---------------- edge transform-scatter GEMM ----------------
// Each block: 32 edges, all same relation (bucketed, padded with -1).
// y_e = x[src_e] @ W[rel] * inv_cnt[dst_e,rel], atomicAdd into acc[dst_e].

template <int D, int O>
__global__ __launch_bounds__(256) void edge_gemm(
    const float* __restrict__ x, const float* __restrict__ W,
    const int* __restrict__ ebuck, const int* __restrict__ src,
    const int* __restrict__ dst, const int* __restrict__ et,
    const float* __restrict__ inv, float* __restrict__ acc)
{
    __shared__ float sxT[D][CHUNK + 1];   // transposed x rows (pad -> conflict-free)
    __shared__ float sW[32][O];           // K-chunk of W[rel]
    __shared__ int   s_e[CHUNK];
    __shared__ int   s_dst[CHUNK];
    __shared__ float s_scl[CHUNK];
    __shared__ int   s_rel;

    int t = threadIdx.x;
    int c = blockIdx.x;

    if (t < CHUNK) s_e[t] = ebuck[c * CHUNK + t];
    if (t == 0) s_rel = -1;
    __syncthreads();
    if (t == 0) {
        for (int j = 0; j < CHUNK; ++j)
            if (s_e[j] >= 0) { s_rel = et[s_e[j]]; break; }
    }
    __syncthreads();
    int rel = s_rel;
    if (rel < 0) return;   // fully padded chunk

    if (t < CHUNK) {
        int e = s_e[t];
        int d = (e >= 0) ? dst[e] : 0;
        s_dst[t] = d;
        s_scl[t] = (e >= 0) ? inv[(size_t)d * NR + rel] : 0.0f;
    }
    // stage x rows transposed: sxT[i][j]
    for (int idx = t; idx < CHUNK * D; idx += 256) {
        int j = idx / D, i = idx % D;
        int e = s_e[j];
        sxT[i][j] = (e >= 0) ? x[(size_t)src[e] * D + i] : 0.0f;
    }

    constexpr int TO  = O / 4;        // o-groups (each covers 4 outputs)
    constexpr int TG  = 256 / TO;     // edge-groups
    constexpr int EPG = CHUNK / TG;   // edges per thread
    int to = t % TO;
    int te = t / TO;
    int je0 = te * EPG;

    float racc[EPG][4];
#pragma unroll
    for (int m = 0; m < EPG; ++m)
#pragma unroll
        for (int q = 0; q < 4; ++q) racc[m][q] = 0.0f;

    for (int kc = 0; kc < D; kc += 32) {
        __syncthreads();
        for (int idx = t; idx < 32 * O; idx += 256) {
            int ii = idx / O, oo = idx % O;
            sW[ii][oo] = W[(size_t)rel * D * O + (size_t)(kc + ii) * O + oo];
        }
        __syncthreads();
#pragma unroll
        for (int ii = 0; ii < 32; ++ii) {
            int i = kc + ii;
            float4 b = *(const float4*)&sW[ii][to * 4];
#pragma unroll
            for (int m = 0; m < EPG; ++m) {
                float a = sxT[i][je0 + m];
                racc[m][0] += a * b.x;
                racc[m][1] += a * b.y;
                racc[m][2] += a * b.z;
                racc[m][3] += a * b.w;
            }
        }
    }

#pragma unroll
    for (int m = 0; m < EPG; ++m) {
        int j = je0 + m;
        int e = s_e[j];
        if (e < 0) continue;
        float scl = s_scl[j];
        float* ap = acc + (size_t)s_dst[j] * O + to * 4;
#pragma unroll
        for (int q = 0; q < 4; ++q) atomicAdd(&ap[q], racc[m][q] * scl);
    }
}

// ---------------- epilogue: root GEMM + bias + relu/resid/LN ----------------
// MODE 0: relu + LN        (layer 1)
// MODE 1: relu + identity + LN  (layer 2, D==O==128)
// MODE 2: relu only        (layer 3)
// MODE 3: plain            (layer 4)

template <int D, int O, int MODE>
__global__ __launch_bounds__(256) void epilogue_kernel(
    const float* __restrict__ x, const float* __restrict__ Wr,
    const float* __restrict__ bias, const float* __restrict__ acc,
    const float* __restrict__ gamma, const float* __restrict__ beta,
    float* __restrict__ out)
{
    constexpr int NT  = 16;
    constexpr int G   = 256 / O;   // node groups
    constexpr int NPT = NT / G;    // nodes per thread
    __shared__ float sx[NT][D];
    __shared__ float sW[32][O];

    int t  = threadIdx.x;
    int n0 = blockIdx.x * NT;
    int o  = t % O;
    int ng = t / O;

    for (int idx = t; idx < NT * D; idx += 256) {
        int j = idx / D, i = idx % D;
        sx[j][i] = x[(size_t)(n0 + j) * D + i];
    }

    float r[NPT];
#pragma unroll
    for (int k = 0; k < NPT; ++k) r[k] = 0.0f;

    for (int kc = 0; kc < D; kc += 32) {
        __syncthreads();
        for (int idx = t; idx < 32 * O; idx += 256) {
            int ii = idx / O, oo = idx % O;
            sW[ii][oo] = Wr[(size_t)(kc + ii) * O + oo];
        }
        __syncthreads();
#pragma unroll
        for (int ii = 0; ii < 32; ++ii) {
            float w = sW[ii][o];
#pragma unroll
            for (int k = 0; k < NPT; ++k)
                r[k] += sx[ng + G * k][kc + ii] * w;
        }
    }

    float bo = bias[o];
    float vv[NPT];
#pragma unroll
    for (int k = 0; k < NPT; ++k) {
        int n = n0 + ng + G * k;
        float v = r[k] + acc[(size_t)n * O + o] + bo;
        if constexpr (MODE <= 2) v = fmaxf(v, 0.0f);
        if constexpr (MODE == 1) v += sx[ng + G * k][o];   // residual (D==O)
        vv[k] = v;
    }

    if constexpr (MODE == 0 || MODE == 1) {
        // LayerNorm over O=128 values (2 waves per node group)
        __shared__ float sS[4][NPT], sQ[4][NPT];
        int wid = t >> 6;
#pragma unroll
        for (int k = 0; k < NPT; ++k) {
            float s1 = vv[k], s2 = vv[k] * vv[k];
#pragma unroll
            for (int off = 32; off >= 1; off >>= 1) {
                s1 += __shfl_xor(s1, off, 64);
                s2 += __shfl_xor(s2, off, 64);
            }
            if ((t & 63) == 0) { sS[wid][k] = s1; sQ[wid][k] = s2; }
        }
        __syncthreads();
        float go = gamma[o], bto = beta[o];
#pragma unroll
        for (int k = 0; k < NPT; ++k) {
            float s1 = sS[2 * ng][k] + sS[2 * ng + 1][k];
            float s2 = sQ[2 * ng][k] + sQ[2 * ng + 1][k];
            float mu  = s1 * (1.0f / O);
            float var = s2 * (1.0f / O) - mu * mu;
            float rs  = rsqrtf(var + 1e-5f);
            int n = n0 + ng + G * k;
            out[(size_t)n * O + o] = (vv[k] - mu) * rs * go + bto;
        }
    } else {
#pragma unroll
        for (int k = 0; k < NPT; ++k) {
            int n = n0 + ng + G * k;
            out[(size_t)n * O + o] = vv[k];
        }
    }
}

// ---------------- host launch ----------------

extern "C" void kernel_launch(void* const* d_in, const int* in_sizes, int n_in,
                              void* d_out, int out_size, void* d_ws, size_t ws_size,
                              hipStream_t stream) {
    const float* emb = (const float*)d_in[0];
    const float* W1  = (const float*)d_in[1];
    const float* R1  = (const float*)d_in[2];
    const float* B1  = (const float*)d_in[3];
    const float* W2  = (const float*)d_in[4];
    const float* R2  = (const float*)d_in[5];
    const float* B2  = (const float*)d_in[6];
    const float* W3  = (const float*)d_in[7];
    const float* R3  = (const float*)d_in[8];
    const float* B3  = (const float*)d_in[9];
    const float* W4  = (const float*)d_in[10];
    const float* R4  = (const float*)d_in[11];
    const float* B4  = (const float*)d_in[12];
    const float* g1  = (const float*)d_in[13];
    const float* b1  = (const float*)d_in[14];
    const float* g2  = (const float*)d_in[15];
    const float* b2  = (const float*)d_in[16];
    const int*   ei  = (const int*)d_in[17];
    const int*   et  = (const int*)d_in[18];
    const int* srcp = ei;
    const int* dstp = ei + NE;

    char* ws = (char*)d_ws;
    // layout (bytes):
    // cnt   u32[800000]          @ 0
    // inv   f32[800000]          @ 3,200,000
    // meta  i32[64]              @ 6,400,000   (off[0..8]; relcnt @ +16; cursor @ +24)
    // ebuck i32[640256]          @ 6,400,256
    // acc   f32[100000*128]      @ 8,961,280
    // x1    f32[100000*128]      @ 60,161,280
    // x2    f32[100000*128]      @ 111,361,280
    // x3    f32[100000*64]       @ 162,561,280  (end 188,161,280)
    if (ws_size < 188161280u) return;
    unsigned* cnt    = (unsigned*)(ws + 0);
    float*    inv    = (float*)(ws + 3200000);
    int*      meta   = (int*)(ws + 6400000);
    int*      off    = meta;
    unsigned* relcnt = (unsigned*)(meta + 16);
    unsigned* cursor = (unsigned*)(meta + 24);
    int*      ebuck  = (int*)(ws + 6400256);
    float*    acc    = (float*)(ws + 8961280);
    float*    x1     = (float*)(ws + 60161280);
    float*    x2     = (float*)(ws + 111361280);
    float*    x3     = (float*)(ws + 162561280);
    float*    outp   = (float*)d_out;

    hipMemsetAsync(cnt, 0, 3200000, stream);
    hipMemsetAsync(meta, 0, 256, stream);
    hipMemsetAsync(ebuck, 0xFF, (size_t)EBUCK_N * 4, stream);

    count_kernel<<<(NE + EPB - 1) / EPB, 256, 0, stream>>>(dstp, et, cnt, relcnt);
    offsets_kernel<<<1, 1, 0, stream>>>(relcnt, off);
    fill_kernel<<<(NE + EPB - 1) / EPB, 256, 0, stream>>>(et, off, cursor, ebuck);
    inv_kernel<<<(NN * NR + 255) / 256, 256, 0, stream>>>(cnt, inv);

    // Layer 1: emb(D=64) -> x1(O=128), relu + LN(g1,b1)
    hipMemsetAsync(acc, 0, (size_t)NN * 128 * 4, stream);
    edge_gemm<64, 128><<<NCHUNKS, 256, 0, stream>>>(emb, W1, ebuck, srcp, dstp, et, inv, acc);
    epilogue_kernel<64, 128, 0><<<NN / 16, 256, 0, stream>>>(emb, R1, B1, acc, g1, b1, x1);

    // Layer 2: x1(128) -> x2(128), relu + residual + LN(g2,b2)
    hipMemsetAsync(acc, 0, (size_t)NN * 128 * 4, stream);
    edge_gemm<128, 128><<<NCHUNKS, 256, 0, stream>>>(x1, W2, ebuck, srcp, dstp, et, inv, acc);
    epilogue_kernel<128, 128, 1><<<NN / 16, 256, 0, stream>>>(x1, R2, B2, acc, g2, b2, x2);

    // Layer 3: x2(128) -> x3(64), relu
    hipMemsetAsync(acc, 0, (size_t)NN * 64 * 4, stream);
    edge_gemm<128, 64><<<NCHUNKS, 256, 0, stream>>>(x2, W3, ebuck, srcp, dstp, et, inv, acc);
    epilogue_kernel<128, 64, 2><<<NN / 16, 256, 0, stream>>>(x2, R3, B3, acc, nullptr, nullptr, x3);

    // Layer 4: x3(64) -> out(64), plain
    hipMemsetAsync(acc, 0, (size_t)NN * 64 * 4, stream);
    edge_gemm<64, 64><<<NCHUNKS, 256, 0, stream>>>(x3, W4, ebuck, srcp, dstp, et, inv, acc);
    epilogue_kernel<64, 64, 3><<<NN / 16, 256, 0, stream>>>(x3, R4, B4, acc, nullptr, nullptr, outp);
}

// Round 3
// 2441.497 us; speedup vs baseline: 4.2476x; 1.9590x over previous
//
#include <hip/hip_runtime.h>
#include <math.h>

#define NN 100000
#define NR 8
#define NE 640000
#define SEGN (NN * NR)                 // 800000
#define SPB 2048                       // segments per scan block
#define NSB ((SEGN + SPB - 1) / SPB)   // 391

// ---------------- preprocessing: CSR by (dst, rel) ----------------

__global__ __launch_bounds__(256) void count_kernel(
    const int* __restrict__ dst, const int* __restrict__ et, unsigned* __restrict__ cnt) {
    int e = blockIdx.x * 256 + threadIdx.x;
    if (e < NE) atomicAdd(&cnt[(size_t)dst[e] * NR + et[e]], 1u);
}

__global__ __launch_bounds__(256) void scan1_kernel(
    const unsigned* __restrict__ cnt, unsigned* __restrict__ bsum) {
    __shared__ unsigned red[256];
    int b = blockIdx.x, t = threadIdx.x;
    int i0 = b * SPB;
    unsigned s = 0;
#pragma unroll
    for (int k = 0; k < SPB / 256; ++k) {
        int i = i0 + k * 256 + t;
        if (i < SEGN) s += cnt[i];
    }
    red[t] = s;
    __syncthreads();
    for (int off = 128; off >= 1; off >>= 1) {
        if (t < off) red[t] += red[t + off];
        __syncthreads();
    }
    if (t == 0) bsum[b] = red[0];
}

__global__ __launch_bounds__(512) void scan2_kernel(
    unsigned* __restrict__ bsum, int* __restrict__ segoff) {
    __shared__ unsigned buf[512];
    int t = threadIdx.x;
    unsigned v = (t < NSB) ? bsum[t] : 0u;
    buf[t] = v;
    __syncthreads();
    for (int off = 1; off < 512; off <<= 1) {
        unsigned w = (t >= off) ? buf[t - off] : 0u;
        __syncthreads();
        buf[t] += w;
        __syncthreads();
    }
    if (t < NSB) bsum[t] = buf[t] - v;   // exclusive block offsets
    if (t == 0) segoff[SEGN] = NE;
}

__global__ __launch_bounds__(256) void scan3_kernel(
    const unsigned* __restrict__ cnt, const unsigned* __restrict__ bsum,
    int* __restrict__ segoff) {
    __shared__ unsigned lc[SPB];      // 8 KB
    __shared__ unsigned tsum[256];
    int b = blockIdx.x, t = threadIdx.x;
    int i0 = b * SPB;
#pragma unroll
    for (int k = 0; k < SPB / 256; ++k) {
        int i = i0 + k * 256 + t;
        lc[k * 256 + t] = (i < SEGN) ? cnt[i] : 0u;
    }
    __syncthreads();
    unsigned s = 0;
#pragma unroll
    for (int k = 0; k < 8; ++k) s += lc[t * 8 + k];
    tsum[t] = s;
    __syncthreads();
    for (int off = 1; off < 256; off <<= 1) {
        unsigned w = (t >= off) ? tsum[t - off] : 0u;
        __syncthreads();
        tsum[t] += w;
        __syncthreads();
    }
    unsigned base = bsum[b] + tsum[t] - s;   // exclusive prefix for this thread's 8
#pragma unroll
    for (int k = 0; k < 8; ++k) {
        unsigned c = lc[t * 8 + k];
        lc[t * 8 + k] = base;
        base += c;
    }
    __syncthreads();
#pragma unroll
    for (int k = 0; k < SPB / 256; ++k) {
        int i = i0 + k * 256 + t;
        if (i < SEGN) segoff[i] = (int)lc[k * 256 + t];
    }
}

__global__ __launch_bounds__(256) void fill_kernel(
    const int* __restrict__ src, const int* __restrict__ dst, const int* __restrict__ et,
    const int* __restrict__ segoff, unsigned* __restrict__ cursor, int* __restrict__ esrc) {
    int e = blockIdx.x * 256 + threadIdx.x;
    if (e >= NE) return;
    int seg = dst[e] * NR + et[e];
    int pos = segoff[seg] + (int)atomicAdd(&cursor[seg], 1u);
    esrc[pos] = src[e];
}

// ---------------- fused layer: gather-mean + 9-way GEMM + epilogue ----------------
// r = 0..7: agg_r[node] = mean_{edges} x[src]  (CSR gather), times W[r]
// r = 8   : agg = x[node] itself, times Wr  (root term)
// epilogue: + bias, MODE 0: relu+LN; 1: relu+resid+LN; 2: relu; 3: plain

template <int D, int O, int NT, int MODE>
__global__ __launch_bounds__(256) void fused_layer(
    const float* __restrict__ x, const float* __restrict__ W, const float* __restrict__ Wr,
    const float* __restrict__ bias, const float* __restrict__ gamma, const float* __restrict__ beta,
    const int* __restrict__ segoff, const int* __restrict__ esrc, float* __restrict__ out)
{
    constexpr int PAD = NT + 4;        // 16B-aligned row stride
    constexpr int TO  = O / 4;         // output quads
    constexpr int NG  = 256 / TO;      // node groups
    constexpr int NPT = NT / NG;       // nodes per thread (=8)
    constexpr int JPW = NT / 4;        // nodes per wave (gather)
    static_assert(NPT == 8, "mapping assumes 8 nodes/thread");

    __shared__ float saggT[D][PAD];    // transposed agg tile
    __shared__ float sW[32 * O];       // K-chunk of W

    int t  = threadIdx.x;
    int to = t % TO, tj = t / TO;
    int n0 = blockIdx.x * NT;
    int wv = t >> 6, ln = t & 63;

    float racc[NPT][4];
#pragma unroll
    for (int m = 0; m < NPT; ++m)
#pragma unroll
        for (int q = 0; q < 4; ++q) racc[m][q] = 0.0f;

    for (int r = 0; r <= NR; ++r) {
        __syncthreads();               // previous GEMM done reading saggT
        // ---- gather into saggT (wave per node, lane per dim) ----
        for (int jj = 0; jj < JPW; ++jj) {
            int j = wv * JPW + jj;
            int n = n0 + j;
            float s0 = 0.0f, s1 = 0.0f;
            if (n < NN) {
                if (r < NR) {
                    int seg = n * NR + r;
                    int e0 = segoff[seg], e1 = segoff[seg + 1];
                    for (int e = e0; e < e1; ++e) {
                        int sN = esrc[e];
                        const float* xp = x + (size_t)sN * D;
                        s0 += xp[ln];
                        if (D == 128) s1 += xp[64 + ln];
                    }
                    int c = e1 - e0;
                    float scale = (c > 0) ? (1.0f / (float)c) : 0.0f;
                    s0 *= scale; s1 *= scale;
                } else {
                    const float* xp = x + (size_t)n * D;
                    s0 = xp[ln];
                    if (D == 128) s1 = xp[64 + ln];
                }
            }
            saggT[ln][j] = s0;
            if (D == 128) saggT[64 + ln][j] = s1;
        }
        const float* Wsel = (r < NR) ? (W + (size_t)r * D * O) : Wr;
        for (int kc = 0; kc < D; kc += 32) {
            __syncthreads();           // saggT ready / prev chunk done with sW
#pragma unroll
            for (int idx = t; idx < 32 * O; idx += 256) sW[idx] = Wsel[(size_t)kc * O + idx];
            __syncthreads();
#pragma unroll 8
            for (int ii = 0; ii < 32; ++ii) {
                float4 b4 = *(const float4*)&sW[ii * O + to * 4];
                float4 a1 = *(const float4*)&saggT[kc + ii][tj * 8];
                float4 a2 = *(const float4*)&saggT[kc + ii][tj * 8 + 4];
#define FMA4(m, a) \
                racc[m][0] += (a) * b4.x; racc[m][1] += (a) * b4.y; \
                racc[m][2] += (a) * b4.z; racc[m][3] += (a) * b4.w;
                FMA4(0, a1.x) FMA4(1, a1.y) FMA4(2, a1.z) FMA4(3, a1.w)
                FMA4(4, a2.x) FMA4(5, a2.y) FMA4(6, a2.z) FMA4(7, a2.w)
#undef FMA4
            }
        }
    }

    // ---- epilogue ----
    float4 bb = *(const float4*)&bias[to * 4];
    float4 gg = make_float4(0, 0, 0, 0), be = make_float4(0, 0, 0, 0);
    if constexpr (MODE == 0 || MODE == 1) {
        gg = *(const float4*)&gamma[to * 4];
        be = *(const float4*)&beta[to * 4];
    }
#pragma unroll
    for (int m = 0; m < NPT; ++m) {
        int n = n0 + tj * NPT + m;
        bool valid = (n < NN);
        float v0 = racc[m][0] + bb.x;
        float v1 = racc[m][1] + bb.y;
        float v2 = racc[m][2] + bb.z;
        float v3 = racc[m][3] + bb.w;
        if constexpr (MODE <= 2) {
            v0 = fmaxf(v0, 0.0f); v1 = fmaxf(v1, 0.0f);
            v2 = fmaxf(v2, 0.0f); v3 = fmaxf(v3, 0.0f);
        }
        if constexpr (MODE == 1) {
            if (valid) {
                float4 xr = *(const float4*)&x[(size_t)n * D + to * 4];  // D==O==128
                v0 += xr.x; v1 += xr.y; v2 += xr.z; v3 += xr.w;
            }
        }
        if constexpr (MODE == 0 || MODE == 1) {
            // LN over O=128: 32 consecutive lanes (same tj) hold one node's row
            float s1 = v0 + v1 + v2 + v3;
            float s2 = v0 * v0 + v1 * v1 + v2 * v2 + v3 * v3;
#pragma unroll
            for (int off = 1; off < 32; off <<= 1) {
                s1 += __shfl_xor(s1, off, 64);
                s2 += __shfl_xor(s2, off, 64);
            }
            float mu  = s1 * (1.0f / O);
            float var = s2 * (1.0f / O) - mu * mu;
            float rs  = rsqrtf(var + 1e-5f);
            v0 = (v0 - mu) * rs * gg.x + be.x;
            v1 = (v1 - mu) * rs * gg.y + be.y;
            v2 = (v2 - mu) * rs * gg.z + be.z;
            v3 = (v3 - mu) * rs * gg.w + be.w;
        }
        if (valid) {
            *(float4*)&out[(size_t)n * O + to * 4] = make_float4(v0, v1, v2, v3);
        }
    }
}

// ---------------- host launch ----------------

extern "C" void kernel_launch(void* const* d_in, const int* in_sizes, int n_in,
                              void* d_out, int out_size, void* d_ws, size_t ws_size,
                              hipStream_t stream) {
    const float* emb = (const float*)d_in[0];
    const float* W1  = (const float*)d_in[1];
    const float* R1  = (const float*)d_in[2];
    const float* B1  = (const float*)d_in[3];
    const float* W2  = (const float*)d_in[4];
    const float* R2  = (const float*)d_in[5];
    const float* B2  = (const float*)d_in[6];
    const float* W3  = (const float*)d_in[7];
    const float* R3  = (const float*)d_in[8];
    const float* B3  = (const float*)d_in[9];
    const float* W4  = (const float*)d_in[10];
    const float* R4  = (const float*)d_in[11];
    const float* B4  = (const float*)d_in[12];
    const float* g1  = (const float*)d_in[13];
    const float* b1  = (const float*)d_in[14];
    const float* g2  = (const float*)d_in[15];
    const float* b2  = (const float*)d_in[16];
    const int*   ei  = (const int*)d_in[17];
    const int*   et  = (const int*)d_in[18];
    const int* srcp = ei;
    const int* dstp = ei + NE;

    char* ws = (char*)d_ws;
    // layout (bytes):
    // cnt    u32[800000]        @ 0            (3,200,000)
    // segoff i32[800001]        @ 3,200,000    (3,200,004 -> pad 3,200,016)
    // cursor u32[800000]        @ 6,400,016    (3,200,000)
    // bsum   u32[512]           @ 9,600,016    (2,048 -> pad to 9,602,080)
    // esrc   i32[640000]        @ 9,602,080    (2,560,000)
    // x1     f32[100000*128]    @ 12,162,080   (51,200,000)
    // x2     f32[100000*128]    @ 63,362,080   (51,200,000)
    // x3     f32[100000*64]     @ 114,562,080  (25,600,000) end 140,162,080
    if (ws_size < 140162080u) return;
    unsigned* cnt    = (unsigned*)(ws + 0);
    int*      segoff = (int*)(ws + 3200000);
    unsigned* cursor = (unsigned*)(ws + 6400016);
    unsigned* bsum   = (unsigned*)(ws + 9600016);
    int*      esrc   = (int*)(ws + 9602080);
    float*    x1     = (float*)(ws + 12162080);
    float*    x2     = (float*)(ws + 63362080);
    float*    x3     = (float*)(ws + 114562080);
    float*    outp   = (float*)d_out;

    hipMemsetAsync(cnt, 0, 3200000, stream);
    hipMemsetAsync(cursor, 0, 3200000, stream);

    count_kernel<<<(NE + 255) / 256, 256, 0, stream>>>(dstp, et, cnt);
    scan1_kernel<<<NSB, 256, 0, stream>>>(cnt, bsum);
    scan2_kernel<<<1, 512, 0, stream>>>(bsum, segoff);
    scan3_kernel<<<NSB, 256, 0, stream>>>(cnt, bsum, segoff);
    fill_kernel<<<(NE + 255) / 256, 256, 0, stream>>>(srcp, dstp, et, segoff, cursor, esrc);

    // Layer 1: emb(64) -> x1(128), relu+LN
    fused_layer<64, 128, 64, 0><<<(NN + 63) / 64, 256, 0, stream>>>(
        emb, W1, R1, B1, g1, b1, segoff, esrc, x1);
    // Layer 2: x1(128) -> x2(128), relu+resid+LN
    fused_layer<128, 128, 64, 1><<<(NN + 63) / 64, 256, 0, stream>>>(
        x1, W2, R2, B2, g2, b2, segoff, esrc, x2);
    // Layer 3: x2(128) -> x3(64), relu
    fused_layer<128, 64, 128, 2><<<(NN + 127) / 128, 256, 0, stream>>>(
        x2, W3, R3, B3, nullptr, nullptr, segoff, esrc, x3);
    // Layer 4: x3(64) -> out(64), plain
    fused_layer<64, 64, 128, 3><<<(NN + 127) / 128, 256, 0, stream>>>(
        x3, W4, R4, B4, nullptr, nullptr, segoff, esrc, outp);
}